// Round 3
// baseline (229.337 us; speedup 1.0000x reference)
//
#include <hip/hip_runtime.h>
#include <hip/hip_bf16.h>

#define N_ROWS 8192
#define N_HALF 4096
#define DIM    2048
#define INV_T  2.0f   // 1/TEMP, TEMP=0.5
#define NB     32     // 8192 / 256
#define NPAIR  528    // NB*(NB+1)/2
#define NPH    64     // DIM / 32  (K-half phases)

typedef __attribute__((ext_vector_type(8))) short bf16x8;
typedef __attribute__((ext_vector_type(4))) float f32x4;

__device__ __forceinline__ float bf2f(short s) {
  return __uint_as_float(((unsigned int)(unsigned short)s) << 16);
}

__device__ __forceinline__ short f2bf(float x) {
  unsigned int u = __float_as_uint(x);
  u += 0x7fffu + ((u >> 16) & 1u);
  return (short)(u >> 16);
}

__device__ __forceinline__ void gload_lds16(const void* g, void* l) {
  __builtin_amdgcn_global_load_lds(
      (const __attribute__((address_space(1))) unsigned int*)g,
      (__attribute__((address_space(3))) unsigned int*)l, 16, 0, 0);
}

// ---------------------------------------------------------------------------
// Kernel 1: L2-normalize rows of x_i / x_j, write bf16 z (8192 x 2048)
// ---------------------------------------------------------------------------
__global__ __launch_bounds__(256) void normalize_k(
    const float* __restrict__ xi, const float* __restrict__ xj,
    short* __restrict__ z)
{
  const int row = blockIdx.x;
  const int t   = threadIdx.x;
  const float* src = (row < N_HALF) ? (xi + (size_t)row * DIM)
                                    : (xj + (size_t)(row - N_HALF) * DIM);
  const float4* src4 = (const float4*)src;
  float4 v0 = src4[t * 2];
  float4 v1 = src4[t * 2 + 1];
  float ss = v0.x*v0.x + v0.y*v0.y + v0.z*v0.z + v0.w*v0.w
           + v1.x*v1.x + v1.y*v1.y + v1.z*v1.z + v1.w*v1.w;
  #pragma unroll
  for (int m = 1; m < 64; m <<= 1) ss += __shfl_xor(ss, m, 64);
  __shared__ float red[4];
  if ((t & 63) == 0) red[t >> 6] = ss;
  __syncthreads();
  float total = red[0] + red[1] + red[2] + red[3];
  float scale = 1.0f / fmaxf(sqrtf(total), 1e-12f);

  float f[8] = {v0.x, v0.y, v0.z, v0.w, v1.x, v1.y, v1.z, v1.w};
  bf16x8 pack;
  #pragma unroll
  for (int e = 0; e < 8; ++e) pack[e] = f2bf(f[e] * scale);
  *((bf16x8*)(z + (size_t)row * DIM) + t) = pack;
}

// ---------------------------------------------------------------------------
// Kernel 2: positives pos[i] = z_i . z_{i +/- N}, self[i] = z_i . z_i (bf16)
// ---------------------------------------------------------------------------
__global__ __launch_bounds__(256) void posself_k(
    const short* __restrict__ z, float* __restrict__ pos,
    float* __restrict__ selfd)
{
  const int i = blockIdx.x;
  const int j = (i < N_HALF) ? (i + N_HALF) : (i - N_HALF);
  const int t = threadIdx.x;
  const bf16x8 va = ((const bf16x8*)(z + (size_t)i * DIM))[t];
  const bf16x8 vb = ((const bf16x8*)(z + (size_t)j * DIM))[t];
  float sp = 0.f, ss = 0.f;
  #pragma unroll
  for (int e = 0; e < 8; ++e) {
    float fa = bf2f(va[e]), fb = bf2f(vb[e]);
    sp += fa * fb;
    ss += fa * fa;
  }
  #pragma unroll
  for (int m = 1; m < 64; m <<= 1) {
    sp += __shfl_xor(sp, m, 64);
    ss += __shfl_xor(ss, m, 64);
  }
  __shared__ float rp[4], rs[4];
  if ((t & 63) == 0) { rp[t >> 6] = sp; rs[t >> 6] = ss; }
  __syncthreads();
  if (t == 0) {
    pos[i]   = rp[0] + rp[1] + rp[2] + rp[3];
    selfd[i] = rs[0] + rs[1] + rs[2] + rs[3];
  }
}

// ---------------------------------------------------------------------------
// Kernel 3: symmetric fused sim-tile + exp row/col sums, 256x256 tiles.
// 8 waves (2M x 4N), per-wave 128x64 output (8x4 16x16x32 frags).
// Pipelined LDS: 4 slots per matrix, slot = one K-half (256 rows x 32 K,
// 16 KiB).  Stage K-half p+3 during phase p; counted vmcnt(8) at each
// phase head (never 0 until drain).  Raw s_barrier (no vmcnt(0) drain).
//
// LDS layout per slot (swizzled, bank-conflict-free ds_read_b128):
//   LDS row q (128 B) holds logical rows (2q, 2q+1); 16B slot index
//   s = ((r&1)*4 + k4) ^ (q&7), q = r>>1, k4 = k-offset/8.
// Staged via inverse-swizzled GLOBAL source + linear gload_lds dest
// (swizzle involution on both sides).
// ---------------------------------------------------------------------------
__global__ __launch_bounds__(512) void simexp_k(
    const short* __restrict__ z, float* __restrict__ denom)
{
  __shared__ char lds[131072];           // A: 4x16 KiB, B: 4x16 KiB
  char* ldsA = lds;
  char* ldsB = lds + 65536;

  const int t    = threadIdx.x;
  const int wave = t >> 6, lane = t & 63;
  const int wr   = wave >> 2, wc = wave & 3;   // 2M x 4N wave grid

  // XCD-aware swizzle (528 % 8 == 0 -> bijective), then triangular decode
  const int bid = blockIdx.x;
  int rem = (bid & 7) * (NPAIR / 8) + (bid >> 3);
  int bi = 0;
  while (rem >= NB - bi) { rem -= NB - bi; ++bi; }
  const int bj   = bi + rem;
  const int row0 = bi * 256;
  const int col0 = bj * 256;

  // ---- staging source offsets (swizzle-inverse of linear LDS dest) ----
  // thread t writes LDS bytes [t*16, +16) of chunk c (c*8192); decompose:
  const int sq  = t >> 3;                     // LDS row (chunk 0)
  const int ss0 = (t & 7) ^ (sq & 7);         // unswizzled slot
  const int sr  = 2 * sq + (ss0 >> 2);        // logical row 0..127
  const int sk4 = ss0 & 3;                    // 16B k-chunk
  const short* zA = z + (size_t)(row0 + sr) * DIM + sk4 * 8;
  const short* zB = z + (size_t)(col0 + sr) * DIM + sk4 * 8;
  char* dA = ldsA + wave * 1024;              // wave-uniform LDS dest
  char* dB = ldsB + wave * 1024;

  // ---- ds_read byte offsets (swizzled) ----
  int offA[8], offB[4];
  #pragma unroll
  for (int m = 0; m < 8; ++m) {
    int r = wr * 128 + m * 16 + (lane & 15);
    int q = r >> 1;
    int s = ((lane >> 4) + (r & 1) * 4) ^ (q & 7);
    offA[m] = q * 128 + s * 16;
  }
  #pragma unroll
  for (int n = 0; n < 4; ++n) {
    int r = wc * 64 + n * 16 + (lane & 15);
    int q = r >> 1;
    int s = ((lane >> 4) + (r & 1) * 4) ^ (q & 7);
    offB[n] = q * 128 + s * 16;
  }

  f32x4 acc[8][4] = {};

#define STAGE(kh, slot) do {                                   \
    const short* pa_ = zA + (kh) * 32;                         \
    const short* pb_ = zB + (kh) * 32;                         \
    char* da_ = dA + (slot) * 16384;                           \
    char* db_ = dB + (slot) * 16384;                           \
    gload_lds16(pa_,             da_);                         \
    gload_lds16(pa_ + 128 * DIM, da_ + 8192);                  \
    gload_lds16(pb_,             db_);                         \
    gload_lds16(pb_ + 128 * DIM, db_ + 8192);                  \
  } while (0)

  // prologue: 3 K-halves in flight
  STAGE(0, 0);
  STAGE(1, 1);
  STAGE(2, 2);

  for (int p = 0; p < NPH; ++p) {
    // counted waits: kh p was issued at phase p-3 (9th-newest load group)
    if (p < NPH - 2)       asm volatile("s_waitcnt vmcnt(8)" ::: "memory");
    else if (p == NPH - 2) asm volatile("s_waitcnt vmcnt(4)" ::: "memory");
    else                   asm volatile("s_waitcnt vmcnt(0)" ::: "memory");
    __builtin_amdgcn_s_barrier();
    __builtin_amdgcn_sched_barrier(0);

    const char* Ab = ldsA + (p & 3) * 16384;
    const char* Bb = ldsB + (p & 3) * 16384;
    bf16x8 a[8], b[4];
    #pragma unroll
    for (int m = 0; m < 8; ++m) a[m] = *(const bf16x8*)(Ab + offA[m]);
    #pragma unroll
    for (int n = 0; n < 4; ++n) b[n] = *(const bf16x8*)(Bb + offB[n]);

    if (p <= NPH - 4) STAGE(p + 3, (p + 3) & 3);  // slot (p+3)%4 != p%4; its
                                                  // last readers done at barrier

    __builtin_amdgcn_s_setprio(1);
    #pragma unroll
    for (int m = 0; m < 8; ++m)
      #pragma unroll
      for (int n = 0; n < 4; ++n)
        acc[m][n] = __builtin_amdgcn_mfma_f32_16x16x32_bf16(a[m], b[n],
                                                            acc[m][n], 0, 0, 0);
    __builtin_amdgcn_s_setprio(0);
    __builtin_amdgcn_sched_barrier(0);
  }
#undef STAGE

  // ---- epilogue: exp, then row sums (+ col sums for off-diagonal) ----
  #pragma unroll
  for (int m = 0; m < 8; ++m)
    #pragma unroll
    for (int n = 0; n < 4; ++n)
      #pragma unroll
      for (int r = 0; r < 4; ++r)
        acc[m][n][r] = __expf(acc[m][n][r] * INV_T);

  // row sums: C layout col = lane&15, row = (lane>>4)*4 + reg
  #pragma unroll
  for (int m = 0; m < 8; ++m) {
    #pragma unroll
    for (int r = 0; r < 4; ++r) {
      float s = acc[m][0][r] + acc[m][1][r] + acc[m][2][r] + acc[m][3][r];
      s += __shfl_xor(s, 1, 64);
      s += __shfl_xor(s, 2, 64);
      s += __shfl_xor(s, 4, 64);
      s += __shfl_xor(s, 8, 64);
      if ((lane & 15) == 0) {
        int grow = row0 + wr * 128 + m * 16 + (lane >> 4) * 4 + r;
        atomicAdd(&denom[grow], s);
      }
    }
  }

  if (bi != bj) {
    #pragma unroll
    for (int n = 0; n < 4; ++n) {
      float cs = 0.f;
      #pragma unroll
      for (int m = 0; m < 8; ++m)
        #pragma unroll
        for (int r = 0; r < 4; ++r)
          cs += acc[m][n][r];
      cs += __shfl_xor(cs, 16, 64);
      cs += __shfl_xor(cs, 32, 64);
      if ((lane >> 4) == 0) {
        int gcol = col0 + wc * 64 + n * 16 + (lane & 15);
        atomicAdd(&denom[gcol], cs);
      }
    }
  }
}

// ---------------------------------------------------------------------------
// Kernel 4: loss = mean_i( log(denom_i - exp(self_i/T)) - pos_i/T )
// ---------------------------------------------------------------------------
__global__ __launch_bounds__(256) void loss_k(
    const float* __restrict__ denom, const float* __restrict__ pos,
    const float* __restrict__ selfd, float* __restrict__ out)
{
  const int t = threadIdx.x;
  float acc = 0.f;
  for (int i = t; i < N_ROWS; i += 256) {
    float d = denom[i] - __expf(selfd[i] * INV_T);
    acc += __logf(d) - pos[i] * INV_T;
  }
  #pragma unroll
  for (int m = 1; m < 64; m <<= 1) acc += __shfl_xor(acc, m, 64);
  __shared__ float red[4];
  if ((t & 63) == 0) red[t >> 6] = acc;
  __syncthreads();
  if (t == 0) out[0] = (red[0] + red[1] + red[2] + red[3]) / (float)N_ROWS;
}

// ---------------------------------------------------------------------------
extern "C" void kernel_launch(void* const* d_in, const int* in_sizes, int n_in,
                              void* d_out, int out_size, void* d_ws, size_t ws_size,
                              hipStream_t stream) {
  const float* xi = (const float*)d_in[0];
  const float* xj = (const float*)d_in[1];
  float* out = (float*)d_out;

  char*  ws    = (char*)d_ws;
  short* zb    = (short*)ws;                                   // 32 MiB bf16 z
  float* denom = (float*)(ws + (size_t)N_ROWS * DIM * 2);      // 8192 f32
  float* pos   = denom + N_ROWS;                               // 8192 f32
  float* selfd = pos + N_ROWS;                                 // 8192 f32

  hipMemsetAsync(denom, 0, N_ROWS * sizeof(float), stream);
  normalize_k<<<N_ROWS, 256, 0, stream>>>(xi, xj, zb);
  posself_k<<<N_ROWS, 256, 0, stream>>>(zb, pos, selfd);
  simexp_k<<<NPAIR, 512, 0, stream>>>(zb, denom);
  loss_k<<<1, 256, 0, stream>>>(denom, pos, selfd, out);
}

// Round 4
// 199.934 us; speedup vs baseline: 1.1471x; 1.1471x over previous
//
#include <hip/hip_runtime.h>
#include <hip/hip_bf16.h>

#define N_ROWS 8192
#define N_HALF 4096
#define DIM    2048
#define INV_T  2.0f   // 1/TEMP, TEMP=0.5
#define NBI    32     // 256-row bands
#define NBJ    64     // 128-col blocks
#define NBLK2  1056   // sum_{bi} (64 - 2*bi)
#define NPH    64     // DIM / 32 K-phases

typedef __attribute__((ext_vector_type(8))) short bf16x8;
typedef __attribute__((ext_vector_type(4))) float f32x4;

__device__ __forceinline__ float bf2f(short s) {
  return __uint_as_float(((unsigned int)(unsigned short)s) << 16);
}

__device__ __forceinline__ short f2bf(float x) {
  unsigned int u = __float_as_uint(x);
  u += 0x7fffu + ((u >> 16) & 1u);
  return (short)(u >> 16);
}

__device__ __forceinline__ void gload_lds16(const void* g, void* l) {
  __builtin_amdgcn_global_load_lds(
      (const __attribute__((address_space(1))) unsigned int*)g,
      (__attribute__((address_space(3))) unsigned int*)l, 16, 0, 0);
}

// ---------------------------------------------------------------------------
// Kernel 1: L2-normalize rows of x_i / x_j, write bf16 z (8192 x 2048)
// ---------------------------------------------------------------------------
__global__ __launch_bounds__(256) void normalize_k(
    const float* __restrict__ xi, const float* __restrict__ xj,
    short* __restrict__ z)
{
  const int row = blockIdx.x;
  const int t   = threadIdx.x;
  const float* src = (row < N_HALF) ? (xi + (size_t)row * DIM)
                                    : (xj + (size_t)(row - N_HALF) * DIM);
  const float4* src4 = (const float4*)src;
  float4 v0 = src4[t * 2];
  float4 v1 = src4[t * 2 + 1];
  float ss = v0.x*v0.x + v0.y*v0.y + v0.z*v0.z + v0.w*v0.w
           + v1.x*v1.x + v1.y*v1.y + v1.z*v1.z + v1.w*v1.w;
  #pragma unroll
  for (int m = 1; m < 64; m <<= 1) ss += __shfl_xor(ss, m, 64);
  __shared__ float red[4];
  if ((t & 63) == 0) red[t >> 6] = ss;
  __syncthreads();
  float total = red[0] + red[1] + red[2] + red[3];
  float scale = 1.0f / fmaxf(sqrtf(total), 1e-12f);

  float f[8] = {v0.x, v0.y, v0.z, v0.w, v1.x, v1.y, v1.z, v1.w};
  bf16x8 pack;
  #pragma unroll
  for (int e = 0; e < 8; ++e) pack[e] = f2bf(f[e] * scale);
  *((bf16x8*)(z + (size_t)row * DIM) + t) = pack;
}

// ---------------------------------------------------------------------------
// Kernel 2: positives pos[i] = z_i . z_{i +/- N}, self[i] = z_i . z_i (bf16)
// ---------------------------------------------------------------------------
__global__ __launch_bounds__(256) void posself_k(
    const short* __restrict__ z, float* __restrict__ pos,
    float* __restrict__ selfd)
{
  const int i = blockIdx.x;
  const int j = (i < N_HALF) ? (i + N_HALF) : (i - N_HALF);
  const int t = threadIdx.x;
  const bf16x8 va = ((const bf16x8*)(z + (size_t)i * DIM))[t];
  const bf16x8 vb = ((const bf16x8*)(z + (size_t)j * DIM))[t];
  float sp = 0.f, ss = 0.f;
  #pragma unroll
  for (int e = 0; e < 8; ++e) {
    float fa = bf2f(va[e]), fb = bf2f(vb[e]);
    sp += fa * fb;
    ss += fa * fa;
  }
  #pragma unroll
  for (int m = 1; m < 64; m <<= 1) {
    sp += __shfl_xor(sp, m, 64);
    ss += __shfl_xor(ss, m, 64);
  }
  __shared__ float rp[4], rs[4];
  if ((t & 63) == 0) { rp[t >> 6] = sp; rs[t >> 6] = ss; }
  __syncthreads();
  if (t == 0) {
    pos[i]   = rp[0] + rp[1] + rp[2] + rp[3];
    selfd[i] = rs[0] + rs[1] + rs[2] + rs[3];
  }
}

// ---------------------------------------------------------------------------
// Kernel 3: symmetric fused sim-tile + exp row/col sums, 256x128 tiles.
// Triangle over (32 x 256-row bands) x (64 x 128-col blocks), bj >= 2*bi:
// 1056 blocks.  Row-sums always; col-sums only for bj >= 2*bi+2 (within-band
// tiles are fully covered by row-sums -> no double count).
// 8 waves (4M x 2N), per-wave 64x64 (4x4 16x16x32 frags, 16 MFMA/phase).
// 3-slot LDS rotation (lead-2): A-slot 16 KiB, B-slot 8 KiB -> 72 KiB total,
// 2 blocks/CU.  STAGE = 3 gload_lds16 calls; steady wait vmcnt(3).
// Swizzled LDS (involution on staging-source + ds_read side, linear dest):
//   LDS row q=r>>1 (128 B), 16B slot s = ((r&1)*4 + k4) ^ (q&7).
// ---------------------------------------------------------------------------
__global__ __launch_bounds__(512, 4) void simexp_k(
    const short* __restrict__ z, float* __restrict__ denom)
{
  __shared__ char lds[73728];
  char* ldsA = lds;            // 3 x 16384
  char* ldsB = lds + 49152;    // 3 x 8192

  const int t    = threadIdx.x;
  const int wave = t >> 6, lane = t & 63;
  const int wr   = wave >> 1, wc = wave & 1;   // 4M x 2N wave grid

  // XCD-aware bijective swizzle (1056 = 8*132), then triangular decode
  const int bid = blockIdx.x;
  int rem = (bid & 7) * (NBLK2 / 8) + (bid >> 3);
  int bi = 0;
  while (rem >= NBJ - 2 * bi) { rem -= NBJ - 2 * bi; ++bi; }
  const int bj   = 2 * bi + rem;
  const int row0 = bi * 256;
  const int col0 = bj * 128;

  // staging source offsets (swizzle-inverse of linear LDS dest)
  const int sq  = t >> 3;                     // LDS row within an 8 KiB call
  const int ss0 = (t & 7) ^ (sq & 7);         // unswizzled slot
  const int sr  = 2 * sq + (ss0 >> 2);        // logical row 0..127
  const int sk4 = ss0 & 3;                    // 16B k-chunk
  const short* zA = z + (size_t)(row0 + sr) * DIM + sk4 * 8;
  const short* zB = z + (size_t)(col0 + sr) * DIM + sk4 * 8;
  char* dA = ldsA + wave * 1024;              // wave-uniform LDS dest bases
  char* dB = ldsB + wave * 1024;

  // ds_read byte offsets (swizzled)
  int offA[4], offB[4];
  #pragma unroll
  for (int m = 0; m < 4; ++m) {
    int r = wr * 64 + m * 16 + (lane & 15);
    int q = r >> 1;
    int s = ((lane >> 4) + (r & 1) * 4) ^ (q & 7);
    offA[m] = q * 128 + s * 16;
  }
  #pragma unroll
  for (int n = 0; n < 4; ++n) {
    int r = wc * 64 + n * 16 + (lane & 15);
    int q = r >> 1;
    int s = ((lane >> 4) + (r & 1) * 4) ^ (q & 7);
    offB[n] = q * 128 + s * 16;
  }

  f32x4 acc[4][4] = {};

#define STAGE(kh, slot) do {                                   \
    const short* pa_ = zA + (kh) * 32;                         \
    const short* pb_ = zB + (kh) * 32;                         \
    char* da_ = dA + (slot) * 16384;                           \
    char* db_ = dB + (slot) * 8192;                            \
    gload_lds16(pa_,             da_);                         \
    gload_lds16(pa_ + 128 * DIM, da_ + 8192);                  \
    gload_lds16(pb_,             db_);                         \
  } while (0)

  // prologue: lead-2
  STAGE(0, 0);
  STAGE(1, 1);

  int sl = 0;
  for (int p = 0; p < NPH; ++p) {
    if (p < NPH - 1) asm volatile("s_waitcnt vmcnt(3)" ::: "memory");
    else             asm volatile("s_waitcnt vmcnt(0)" ::: "memory");
    __builtin_amdgcn_s_barrier();
    __builtin_amdgcn_sched_barrier(0);

    const char* Ab = ldsA + sl * 16384;
    const char* Bb = ldsB + sl * 8192;
    bf16x8 a[4], b[4];
    #pragma unroll
    for (int m = 0; m < 4; ++m) a[m] = *(const bf16x8*)(Ab + offA[m]);
    #pragma unroll
    for (int n = 0; n < 4; ++n) b[n] = *(const bf16x8*)(Bb + offB[n]);

    if (p + 2 < NPH) {
      int s2 = sl + 2; if (s2 >= 3) s2 -= 3;   // slot (p+2)%3 == (p-1)%3
      STAGE(p + 2, s2);                        // its readers passed barrier p
    }

    __builtin_amdgcn_s_setprio(1);
    #pragma unroll
    for (int m = 0; m < 4; ++m)
      #pragma unroll
      for (int n = 0; n < 4; ++n)
        acc[m][n] = __builtin_amdgcn_mfma_f32_16x16x32_bf16(a[m], b[n],
                                                            acc[m][n], 0, 0, 0);
    __builtin_amdgcn_s_setprio(0);
    __builtin_amdgcn_sched_barrier(0);

    if (++sl >= 3) sl = 0;
  }
#undef STAGE

  // ---- epilogue ----
  #pragma unroll
  for (int m = 0; m < 4; ++m)
    #pragma unroll
    for (int n = 0; n < 4; ++n)
      #pragma unroll
      for (int r = 0; r < 4; ++r)
        acc[m][n][r] = __expf(acc[m][n][r] * INV_T);

  // row sums: C layout col = lane&15, row = (lane>>4)*4 + reg
  #pragma unroll
  for (int m = 0; m < 4; ++m) {
    #pragma unroll
    for (int r = 0; r < 4; ++r) {
      float s = acc[m][0][r] + acc[m][1][r] + acc[m][2][r] + acc[m][3][r];
      s += __shfl_xor(s, 1, 64);
      s += __shfl_xor(s, 2, 64);
      s += __shfl_xor(s, 4, 64);
      s += __shfl_xor(s, 8, 64);
      if ((lane & 15) == 0) {
        int grow = row0 + wr * 64 + m * 16 + (lane >> 4) * 4 + r;
        atomicAdd(&denom[grow], s);
      }
    }
  }

  // col sums (mirror-tile contribution) — only for out-of-band tiles
  if (bj >= 2 * bi + 2) {
    #pragma unroll
    for (int n = 0; n < 4; ++n) {
      float cs = 0.f;
      #pragma unroll
      for (int m = 0; m < 4; ++m)
        #pragma unroll
        for (int r = 0; r < 4; ++r)
          cs += acc[m][n][r];
      cs += __shfl_xor(cs, 16, 64);
      cs += __shfl_xor(cs, 32, 64);
      if ((lane >> 4) == 0) {
        int gcol = col0 + wc * 64 + n * 16 + (lane & 15);
        atomicAdd(&denom[gcol], cs);
      }
    }
  }
}

// ---------------------------------------------------------------------------
// Kernel 4: loss = mean_i( log(denom_i - exp(self_i/T)) - pos_i/T )
// ---------------------------------------------------------------------------
__global__ __launch_bounds__(256) void loss_k(
    const float* __restrict__ denom, const float* __restrict__ pos,
    const float* __restrict__ selfd, float* __restrict__ out)
{
  const int t = threadIdx.x;
  float acc = 0.f;
  for (int i = t; i < N_ROWS; i += 256) {
    float d = denom[i] - __expf(selfd[i] * INV_T);
    acc += __logf(d) - pos[i] * INV_T;
  }
  #pragma unroll
  for (int m = 1; m < 64; m <<= 1) acc += __shfl_xor(acc, m, 64);
  __shared__ float red[4];
  if ((t & 63) == 0) red[t >> 6] = acc;
  __syncthreads();
  if (t == 0) out[0] = (red[0] + red[1] + red[2] + red[3]) / (float)N_ROWS;
}

// ---------------------------------------------------------------------------
extern "C" void kernel_launch(void* const* d_in, const int* in_sizes, int n_in,
                              void* d_out, int out_size, void* d_ws, size_t ws_size,
                              hipStream_t stream) {
  const float* xi = (const float*)d_in[0];
  const float* xj = (const float*)d_in[1];
  float* out = (float*)d_out;

  char*  ws    = (char*)d_ws;
  short* zb    = (short*)ws;                                   // 32 MiB bf16 z
  float* denom = (float*)(ws + (size_t)N_ROWS * DIM * 2);      // 8192 f32
  float* pos   = denom + N_ROWS;                               // 8192 f32
  float* selfd = pos + N_ROWS;                                 // 8192 f32

  hipMemsetAsync(denom, 0, N_ROWS * sizeof(float), stream);
  normalize_k<<<N_ROWS, 256, 0, stream>>>(xi, xj, zb);
  posself_k<<<N_ROWS, 256, 0, stream>>>(zb, pos, selfd);
  simexp_k<<<NBLK2, 512, 0, stream>>>(zb, denom);
  loss_k<<<1, 256, 0, stream>>>(denom, pos, selfd, out);
}